// Round 3
// baseline (26.229 us; speedup 1.0000x reference)
//
#include <hip/hip_runtime.h>

// Batched 2x2: t2 = x*A; t4=t2^2; t8=t4^2; t16=t8^2;
// ft = A*(I-t2)*(I+t4)*(I+t8)*(I+t16), left-associative.
// Memory-bound streaming: grid-stride, 16B vector io, nontemporal stores.

typedef float floatx4 __attribute__((ext_vector_type(4)));

struct M2 { float a, b, c, d; };  // row-major [ [a,b], [c,d] ]

__device__ __forceinline__ M2 mm(const M2& A, const M2& B) {
    M2 C;
    C.a = fmaf(A.a, B.a, A.b * B.c);
    C.b = fmaf(A.a, B.b, A.b * B.d);
    C.c = fmaf(A.c, B.a, A.d * B.c);
    C.d = fmaf(A.c, B.b, A.d * B.d);
    return C;
}

__global__ void __launch_bounds__(256)
eps_model_kernel(const floatx4* __restrict__ x, const float* __restrict__ A0inv,
                 floatx4* __restrict__ out, int n) {
    const M2 A{A0inv[0], A0inv[1], A0inv[2], A0inv[3]};

    int tid    = blockIdx.x * blockDim.x + threadIdx.x;
    int stride = gridDim.x * blockDim.x;

    for (int i = tid; i < n; i += stride) {
        floatx4 v = x[i];
        M2 M{v.x, v.y, v.z, v.w};

        M2 t2  = mm(M, A);
        M2 t4  = mm(t2, t2);
        M2 t8  = mm(t4, t4);
        M2 t16 = mm(t8, t8);

        M2 p1{1.0f - t2.a, -t2.b, -t2.c, 1.0f - t2.d};   // I - t2
        M2 p2{1.0f + t4.a,  t4.b,  t4.c, 1.0f + t4.d};   // I + t4
        M2 p3{1.0f + t8.a,  t8.b,  t8.c, 1.0f + t8.d};   // I + t8
        M2 p4{1.0f + t16.a, t16.b, t16.c, 1.0f + t16.d}; // I + t16

        M2 r = mm(A, p1);
        r = mm(r, p2);
        r = mm(r, p3);
        r = mm(r, p4);

        floatx4 o;
        o.x = r.a; o.y = r.b; o.z = r.c; o.w = r.d;
        __builtin_nontemporal_store(o, &out[i]);
    }
}

extern "C" void kernel_launch(void* const* d_in, const int* in_sizes, int n_in,
                              void* d_out, int out_size, void* d_ws, size_t ws_size,
                              hipStream_t stream) {
    const floatx4* x   = (const floatx4*)d_in[0];  // [B,2,2] fp32 -> one 16B vec per matrix
    const float*   A0  = (const float*)d_in[1];    // [2,2] fp32
    floatx4*       out = (floatx4*)d_out;          // [B,2,2] fp32

    int n = in_sizes[0] / 4;                       // number of 2x2 matrices (4M)
    int block = 256;
    int grid  = 2048;                              // grid-stride: ~8 iters/thread
    eps_model_kernel<<<grid, block, 0, stream>>>(x, A0, out, n);
}

// Round 4
// 25.206 us; speedup vs baseline: 1.0406x; 1.0406x over previous
//
#include <hip/hip_runtime.h>

// Batched 2x2: t2 = x*A; t4=t2^2; t8=t4^2; t16=t8^2;
// ft = A*(I-t2)*(I+t4)*(I+t8)*(I+t16), left-associative.
// Memory-bound streaming. R4: 2 matrices/thread (split-stride, both streams
// coalesced), plain cached stores (NT stores regressed in R3).

typedef float floatx4 __attribute__((ext_vector_type(4)));

struct M2 { float a, b, c, d; };  // row-major [ [a,b], [c,d] ]

__device__ __forceinline__ M2 mm(const M2& A, const M2& B) {
    M2 C;
    C.a = fmaf(A.a, B.a, A.b * B.c);
    C.b = fmaf(A.a, B.b, A.b * B.d);
    C.c = fmaf(A.c, B.a, A.d * B.c);
    C.d = fmaf(A.c, B.b, A.d * B.d);
    return C;
}

__device__ __forceinline__ floatx4 eval_one(floatx4 v, const M2& A) {
    M2 M{v.x, v.y, v.z, v.w};

    M2 t2  = mm(M, A);
    M2 t4  = mm(t2, t2);
    M2 t8  = mm(t4, t4);
    M2 t16 = mm(t8, t8);

    M2 p1{1.0f - t2.a, -t2.b, -t2.c, 1.0f - t2.d};   // I - t2
    M2 p2{1.0f + t4.a,  t4.b,  t4.c, 1.0f + t4.d};   // I + t4
    M2 p3{1.0f + t8.a,  t8.b,  t8.c, 1.0f + t8.d};   // I + t8
    M2 p4{1.0f + t16.a, t16.b, t16.c, 1.0f + t16.d}; // I + t16

    M2 r = mm(A, p1);
    r = mm(r, p2);
    r = mm(r, p3);
    r = mm(r, p4);

    floatx4 o;
    o.x = r.a; o.y = r.b; o.z = r.c; o.w = r.d;
    return o;
}

__global__ void __launch_bounds__(256)
eps_model_kernel(const floatx4* __restrict__ x, const float* __restrict__ A0inv,
                 floatx4* __restrict__ out, int half) {
    const M2 A{A0inv[0], A0inv[1], A0inv[2], A0inv[3]};

    int t = blockIdx.x * blockDim.x + threadIdx.x;
    if (t >= half) return;

    // Two independent, fully-coalesced streams -> 2 loads in flight per thread.
    floatx4 v0 = x[t];
    floatx4 v1 = x[t + half];

    floatx4 o0 = eval_one(v0, A);
    floatx4 o1 = eval_one(v1, A);

    out[t]        = o0;
    out[t + half] = o1;
}

extern "C" void kernel_launch(void* const* d_in, const int* in_sizes, int n_in,
                              void* d_out, int out_size, void* d_ws, size_t ws_size,
                              hipStream_t stream) {
    const floatx4* x   = (const floatx4*)d_in[0];  // [B,2,2] fp32 -> one 16B vec per matrix
    const float*   A0  = (const float*)d_in[1];    // [2,2] fp32
    floatx4*       out = (floatx4*)d_out;          // [B,2,2] fp32

    int n    = in_sizes[0] / 4;                    // number of 2x2 matrices (4M, even)
    int half = n / 2;
    int block = 256;
    int grid  = (half + block - 1) / block;        // 8192 blocks
    eps_model_kernel<<<grid, block, 0, stream>>>(x, A0, out, half);
}

// Round 5
// 24.708 us; speedup vs baseline: 1.0616x; 1.0202x over previous
//
#include <hip/hip_runtime.h>

// Batched 2x2: t2 = x*A; t4=t2^2; t8=t4^2; t16=t8^2;
// ft = A*(I-t2)*(I+t4)*(I+t8)*(I+t16), left-associative.
// Purely memory-bound streaming kernel: float4 in, float4 out per matrix.
// R1 form restored: one matrix/thread, one-shot grid, plain cached stores.
// (R3 NT-store+grid-stride: -5%. R4 2-per-thread split-stride: neutral.
//  5.4 TB/s effective = 86% of measured 6.29 TB/s copy ceiling.)

struct M2 { float a, b, c, d; };  // row-major [ [a,b], [c,d] ]

__device__ __forceinline__ M2 mm(const M2& A, const M2& B) {
    M2 C;
    C.a = fmaf(A.a, B.a, A.b * B.c);
    C.b = fmaf(A.a, B.b, A.b * B.d);
    C.c = fmaf(A.c, B.a, A.d * B.c);
    C.d = fmaf(A.c, B.b, A.d * B.d);
    return C;
}

__global__ void __launch_bounds__(256)
eps_model_kernel(const float4* __restrict__ x, const float* __restrict__ A0inv,
                 float4* __restrict__ out, int n) {
    int i = blockIdx.x * blockDim.x + threadIdx.x;
    if (i >= n) return;

    const M2 A{A0inv[0], A0inv[1], A0inv[2], A0inv[3]};

    float4 v = x[i];
    M2 M{v.x, v.y, v.z, v.w};

    M2 t2  = mm(M, A);
    M2 t4  = mm(t2, t2);
    M2 t8  = mm(t4, t4);
    M2 t16 = mm(t8, t8);

    M2 p1{1.0f - t2.a, -t2.b, -t2.c, 1.0f - t2.d};   // I - t2
    M2 p2{1.0f + t4.a,  t4.b,  t4.c, 1.0f + t4.d};   // I + t4
    M2 p3{1.0f + t8.a,  t8.b,  t8.c, 1.0f + t8.d};   // I + t8
    M2 p4{1.0f + t16.a, t16.b, t16.c, 1.0f + t16.d}; // I + t16

    M2 r = mm(A, p1);
    r = mm(r, p2);
    r = mm(r, p3);
    r = mm(r, p4);

    out[i] = make_float4(r.a, r.b, r.c, r.d);
}

extern "C" void kernel_launch(void* const* d_in, const int* in_sizes, int n_in,
                              void* d_out, int out_size, void* d_ws, size_t ws_size,
                              hipStream_t stream) {
    const float4* x    = (const float4*)d_in[0];   // [B,2,2] fp32 -> one float4 per matrix
    const float*  A0   = (const float*)d_in[1];    // [2,2] fp32
    float4*       out  = (float4*)d_out;           // [B,2,2] fp32

    int n = in_sizes[0] / 4;                       // number of 2x2 matrices
    int block = 256;
    int grid = (n + block - 1) / block;
    eps_model_kernel<<<grid, block, 0, stream>>>(x, A0, out, n);
}